// Round 2
// baseline (1107.161 us; speedup 1.0000x reference)
//
#include <hip/hip_runtime.h>
#include <hip/hip_bf16.h>

#define T_ 4
#define N_ 50000
#define E_ 800000
#define C_ 128
#define K_ 3

typedef __hip_bfloat16 bf16;
typedef __attribute__((ext_vector_type(4))) float f32x4;
typedef __attribute__((ext_vector_type(8))) short bf16x8;

__device__ inline short bf16bits(float f) {
    bf16 h = __float2bfloat16(f);
    union { bf16 h; short s; } u; u.h = h; return u.s;
}

// ---------------- CSR build ----------------

__global__ void count_kernel(const int* __restrict__ row, int* __restrict__ counts) {
    int e = blockIdx.x * blockDim.x + threadIdx.x;
    if (e < E_) atomicAdd(&counts[row[e]], 1);
}

__global__ __launch_bounds__(1024) void scan_kernel(const int* __restrict__ counts,
                                                    int* __restrict__ starts,
                                                    int* __restrict__ cursors) {
    __shared__ int wsum[16];
    __shared__ int carry_s;
    int tid = threadIdx.x;
    int wave = tid >> 6, lane = tid & 63;
    if (tid == 0) carry_s = 0;
    __syncthreads();
    for (int base = 0; base < N_; base += 1024) {
        int i = base + tid;
        int v = (i < N_) ? counts[i] : 0;
        // intra-wave inclusive scan
        int s = v;
        #pragma unroll
        for (int off = 1; off < 64; off <<= 1) {
            int u = __shfl_up(s, off, 64);
            if (lane >= off) s += u;
        }
        if (lane == 63) wsum[wave] = s;
        __syncthreads();
        if (wave == 0) {
            int w = (lane < 16) ? wsum[lane] : 0;
            #pragma unroll
            for (int off = 1; off < 16; off <<= 1) {
                int u = __shfl_up(w, off, 64);
                if (lane >= off) w += u;
            }
            if (lane < 16) wsum[lane] = w;
        }
        __syncthreads();
        int carry = carry_s;
        int wbase = (wave == 0) ? 0 : wsum[wave - 1];
        int incl = carry + wbase + s;
        if (i < N_) {
            starts[i]  = incl - v;
            cursors[i] = incl - v;
        }
        __syncthreads();
        if (tid == 1023) carry_s = incl;
        __syncthreads();
    }
    if (tid == 0) starts[N_] = carry_s;
}

__global__ void scatter_kernel(const int* __restrict__ row, const int* __restrict__ col,
                               const float* __restrict__ val, int* __restrict__ cursors,
                               int* __restrict__ scol, float* __restrict__ sval) {
    int e = blockIdx.x * blockDim.x + threadIdx.x;
    if (e < E_) {
        int p = atomicAdd(&cursors[row[e]], 1);
        scol[p] = col[e];
        sval[p] = val[e];
    }
}

// ---------------- SpMM 1: tx1[t,n,c] = sum_e val * x[t,col,c]  (f32 gather -> bf16 out) -----------

__global__ __launch_bounds__(512) void spmm1_kernel(const int* __restrict__ starts,
                                                    const int* __restrict__ scol,
                                                    const float* __restrict__ sval,
                                                    const float* __restrict__ x,
                                                    bf16* __restrict__ tx1) {
    int n   = blockIdx.x;
    int tid = threadIdx.x;        // 512 = T_ * C_
    int t = tid >> 7, c = tid & 127;
    int s  = starts[n];
    int e1 = starts[n + 1];
    const float* xt = x + (size_t)t * (N_ * C_) + c;
    float acc = 0.f;
    for (int e = s; e < e1; ++e) {
        acc += sval[e] * xt[(size_t)scol[e] * C_];
    }
    tx1[(size_t)t * (N_ * C_) + (size_t)n * C_ + c] = __float2bfloat16(acc);
}

// ---------------- SpMM 2: tx2 = 2 * (A @ tx1) - x  (bf16 gather -> bf16 out) ----------------

__global__ __launch_bounds__(512) void spmm2_kernel(const int* __restrict__ starts,
                                                    const int* __restrict__ scol,
                                                    const float* __restrict__ sval,
                                                    const bf16* __restrict__ tx1,
                                                    const float* __restrict__ x,
                                                    bf16* __restrict__ tx2) {
    int n   = blockIdx.x;
    int tid = threadIdx.x;
    int t = tid >> 7, c = tid & 127;
    int s  = starts[n];
    int e1 = starts[n + 1];
    const bf16* ht = tx1 + (size_t)t * (N_ * C_) + c;
    float acc = 0.f;
    for (int e = s; e < e1; ++e) {
        acc += sval[e] * __bfloat162float(ht[(size_t)scol[e] * C_]);
    }
    size_t oi = (size_t)t * (N_ * C_) + (size_t)n * C_ + c;
    acc = 2.f * acc - x[oi];
    tx2[oi] = __float2bfloat16(acc);
}

// ---------------- GEMM: out[t] = [x|tx1|tx2][t] @ [W0;W1;W2][t] + bias[t]  (f32 out) -------------
// block: 256 threads (4 waves). Tile: 128 rows x 128 cols, K = 384 in 12 steps of 32.

__global__ __launch_bounds__(256) void gemm_kernel(const float* __restrict__ x,
                                                   const bf16* __restrict__ tx1,
                                                   const bf16* __restrict__ tx2,
                                                   const float* __restrict__ weight,
                                                   const float* __restrict__ bias,
                                                   float* __restrict__ out) {
    int t  = blockIdx.y;
    int m0 = blockIdx.x * 128;
    __shared__ short As[128][40];   // [row][k], +8 pad
    __shared__ short Bs[128][40];   // B^T: [n][k], +8 pad
    int tid  = threadIdx.x;
    int wave = tid >> 6, lane = tid & 63;
    int l15 = lane & 15, l4 = lane >> 4;

    f32x4 acc[2][8];
    for (int i = 0; i < 2; ++i)
        for (int j = 0; j < 8; ++j) acc[i][j] = (f32x4){0.f, 0.f, 0.f, 0.f};

    size_t tslice = (size_t)t * N_ * C_;

    for (int ks = 0; ks < 12; ++ks) {
        int sid = ks >> 2;
        int i0  = (ks & 3) * 32;
        // stage A tile: 128 rows x 32 k  (512 slots of 8 elems, 2 per thread)
        for (int slot = tid; slot < 512; slot += 256) {
            int r = slot >> 2, seg = slot & 3;
            int gr = m0 + r;
            int4 v = {0, 0, 0, 0};
            if (gr < N_) {
                if (sid == 0) {
                    const float* p = x + tslice + (size_t)gr * C_ + i0 + seg * 8;
                    union { int4 v; bf16 h[8]; } u;
                    #pragma unroll
                    for (int j = 0; j < 8; ++j) u.h[j] = __float2bfloat16(p[j]);
                    v = u.v;
                } else {
                    const bf16* p = (sid == 1 ? tx1 : tx2) + tslice + (size_t)gr * C_ + i0 + seg * 8;
                    v = *(const int4*)p;
                }
            }
            *(int4*)&As[r][seg * 8] = v;
        }
        // stage B^T tile: W[t][sid][i0+r][o] (f32) -> Bs[o][r] (bf16)
        const float* W = weight + (((size_t)t * K_ + sid) * C_ + i0) * C_;
        for (int slot = tid; slot < 512; slot += 256) {
            int r = slot >> 4, seg = slot & 15;   // r: k 0..31, seg: 8-col group
            const float* p = W + (size_t)r * C_ + seg * 8;
            #pragma unroll
            for (int j = 0; j < 8; ++j) Bs[seg * 8 + j][r] = bf16bits(p[j]);
        }
        __syncthreads();

        int krow = l4 * 8;
        bf16x8 bfr[8];
        #pragma unroll
        for (int nf = 0; nf < 8; ++nf)
            bfr[nf] = *(bf16x8*)&Bs[nf * 16 + l15][krow];
        #pragma unroll
        for (int mf = 0; mf < 2; ++mf) {
            bf16x8 a = *(bf16x8*)&As[wave * 32 + mf * 16 + l15][krow];
            #pragma unroll
            for (int nf = 0; nf < 8; ++nf)
                acc[mf][nf] = __builtin_amdgcn_mfma_f32_16x16x32_bf16(a, bfr[nf], acc[mf][nf], 0, 0, 0);
        }
        __syncthreads();
    }

    const float* bs = bias + (size_t)t * C_;
    float* ot = out + tslice;
    #pragma unroll
    for (int nf = 0; nf < 8; ++nf) {
        int gc = nf * 16 + l15;
        float bv = bs[gc];
        #pragma unroll
        for (int mf = 0; mf < 2; ++mf) {
            #pragma unroll
            for (int reg = 0; reg < 4; ++reg) {
                int gr = m0 + wave * 32 + mf * 16 + l4 * 4 + reg;
                if (gr < N_) ot[(size_t)gr * C_ + gc] = acc[mf][nf][reg] + bv;
            }
        }
    }
}

// ---------------- launch ----------------

extern "C" void kernel_launch(void* const* d_in, const int* in_sizes, int n_in,
                              void* d_out, int out_size, void* d_ws, size_t ws_size,
                              hipStream_t stream) {
    const float* x      = (const float*)d_in[0];
    const int*   erow   = (const int*)d_in[1];
    const int*   ecol   = (const int*)d_in[2];
    const float* eval   = (const float*)d_in[3];
    const float* weight = (const float*)d_in[4];
    const float* bias   = (const float*)d_in[5];
    float* out = (float*)d_out;

    char* ws = (char*)d_ws;
    size_t off = 0;
    auto alloc = [&](size_t bytes) -> void* {
        void* p = ws + off;
        off += (bytes + 255) & ~(size_t)255;
        return p;
    };
    int*   counts  = (int*)alloc((N_ + 1) * sizeof(int));
    int*   starts  = (int*)alloc((N_ + 1) * sizeof(int));
    int*   cursors = (int*)alloc((size_t)N_ * sizeof(int));
    int*   scol    = (int*)alloc((size_t)E_ * sizeof(int));
    float* sval    = (float*)alloc((size_t)E_ * sizeof(float));
    bf16*  tx1     = (bf16*)alloc((size_t)T_ * N_ * C_ * sizeof(bf16));
    bf16*  tx2     = (bf16*)alloc((size_t)T_ * N_ * C_ * sizeof(bf16));

    hipMemsetAsync(counts, 0, (N_ + 1) * sizeof(int), stream);
    count_kernel<<<(E_ + 255) / 256, 256, 0, stream>>>(erow, counts);
    scan_kernel<<<1, 1024, 0, stream>>>(counts, starts, cursors);
    scatter_kernel<<<(E_ + 255) / 256, 256, 0, stream>>>(erow, ecol, eval, cursors, scol, sval);
    spmm1_kernel<<<N_, 512, 0, stream>>>(starts, scol, sval, x, tx1);
    spmm2_kernel<<<N_, 512, 0, stream>>>(starts, scol, sval, tx1, x, tx2);
    dim3 g((N_ + 127) / 128, T_);
    gemm_kernel<<<g, 256, 0, stream>>>(x, tx1, tx2, weight, bias, out);
}

// Round 3
// 781.795 us; speedup vs baseline: 1.4162x; 1.4162x over previous
//
#include <hip/hip_runtime.h>
#include <hip/hip_bf16.h>

#define T_ 4
#define N_ 50000
#define E_ 800000
#define C_ 128
#define K_ 3
#define UNROLL_ 8

typedef __hip_bfloat16 bf16;
typedef __attribute__((ext_vector_type(4))) float f32x4;
typedef __attribute__((ext_vector_type(8))) short bf16x8;
typedef __attribute__((ext_vector_type(4))) short s16x4;

__device__ inline short bf16bits(float f) {
    bf16 h = __float2bfloat16(f);
    union { bf16 h; short s; } u; u.h = h; return u.s;
}
__device__ inline float bf16f(short s) {
    union { bf16 h; short s; } u; u.s = s; return __bfloat162float(u.h);
}

// ---------------- CSR build ----------------

__global__ void count_kernel(const int* __restrict__ row, int* __restrict__ counts) {
    int e = blockIdx.x * blockDim.x + threadIdx.x;
    if (e < E_) atomicAdd(&counts[row[e]], 1);
}

__global__ __launch_bounds__(1024) void scan_kernel(const int* __restrict__ counts,
                                                    int* __restrict__ starts,
                                                    int* __restrict__ cursors) {
    __shared__ int wsum[16];
    __shared__ int carry_s;
    int tid = threadIdx.x;
    int wave = tid >> 6, lane = tid & 63;
    if (tid == 0) carry_s = 0;
    __syncthreads();
    for (int base = 0; base < N_; base += 1024) {
        int i = base + tid;
        int v = (i < N_) ? counts[i] : 0;
        int s = v;
        #pragma unroll
        for (int off = 1; off < 64; off <<= 1) {
            int u = __shfl_up(s, off, 64);
            if (lane >= off) s += u;
        }
        if (lane == 63) wsum[wave] = s;
        __syncthreads();
        if (wave == 0) {
            int w = (lane < 16) ? wsum[lane] : 0;
            #pragma unroll
            for (int off = 1; off < 16; off <<= 1) {
                int u = __shfl_up(w, off, 64);
                if (lane >= off) w += u;
            }
            if (lane < 16) wsum[lane] = w;
        }
        __syncthreads();
        int carry = carry_s;
        int wbase = (wave == 0) ? 0 : wsum[wave - 1];
        int incl = carry + wbase + s;
        if (i < N_) {
            starts[i]  = incl - v;
            cursors[i] = incl - v;
        }
        __syncthreads();
        if (tid == 1023) carry_s = incl;
        __syncthreads();
    }
    if (tid == 0) starts[N_] = carry_s;
}

__global__ void scatter_kernel(const int* __restrict__ row, const int* __restrict__ col,
                               const float* __restrict__ val, int* __restrict__ cursors,
                               int* __restrict__ scol, float* __restrict__ sval) {
    int e = blockIdx.x * blockDim.x + threadIdx.x;
    if (e < E_) {
        int p = atomicAdd(&cursors[row[e]], 1);
        scol[p] = col[e];
        sval[p] = val[e];
    }
}

// ---------------- SpMM 1: tx1[t,n,c] = sum_e val * x[t,col,c]  (f32x4 gather, ILP-8) -------------
// 128 threads: t = tid>>5, c = 4*(tid&31). Each thread owns 4 channels.

__global__ __launch_bounds__(128) void spmm1_kernel(const int* __restrict__ starts,
                                                    const int* __restrict__ scol,
                                                    const float* __restrict__ sval,
                                                    const float* __restrict__ x,
                                                    bf16* __restrict__ tx1) {
    int n   = blockIdx.x;
    int tid = threadIdx.x;
    int t = tid >> 5, c = (tid & 31) * 4;
    int s  = starts[n];
    int e1 = starts[n + 1];
    const float* xt = x + (size_t)t * (N_ * C_) + c;
    f32x4 acc = {0.f, 0.f, 0.f, 0.f};
    for (int e = s; e < e1; e += UNROLL_) {
        int   cc[UNROLL_];
        float vv[UNROLL_];
        #pragma unroll
        for (int j = 0; j < UNROLL_; ++j) {
            int ee = e + j;
            bool ok = ee < e1;
            cc[j] = ok ? scol[ee] : 0;
            vv[j] = ok ? sval[ee] : 0.f;
        }
        f32x4 g[UNROLL_];
        #pragma unroll
        for (int j = 0; j < UNROLL_; ++j)
            g[j] = *(const f32x4*)(xt + (size_t)cc[j] * C_);
        #pragma unroll
        for (int j = 0; j < UNROLL_; ++j)
            acc += g[j] * vv[j];
    }
    s16x4 o;
    #pragma unroll
    for (int j = 0; j < 4; ++j) o[j] = bf16bits(acc[j]);
    *(s16x4*)(tx1 + (size_t)t * (N_ * C_) + (size_t)n * C_ + c) = o;
}

// ---------------- SpMM 2: tx2 = 2 * (A @ tx1) - x  (bf16x4 gather, ILP-8) ----------------

__global__ __launch_bounds__(128) void spmm2_kernel(const int* __restrict__ starts,
                                                    const int* __restrict__ scol,
                                                    const float* __restrict__ sval,
                                                    const bf16* __restrict__ tx1,
                                                    const float* __restrict__ x,
                                                    bf16* __restrict__ tx2) {
    int n   = blockIdx.x;
    int tid = threadIdx.x;
    int t = tid >> 5, c = (tid & 31) * 4;
    int s  = starts[n];
    int e1 = starts[n + 1];
    const bf16* ht = tx1 + (size_t)t * (N_ * C_) + c;
    f32x4 acc = {0.f, 0.f, 0.f, 0.f};
    for (int e = s; e < e1; e += UNROLL_) {
        int   cc[UNROLL_];
        float vv[UNROLL_];
        #pragma unroll
        for (int j = 0; j < UNROLL_; ++j) {
            int ee = e + j;
            bool ok = ee < e1;
            cc[j] = ok ? scol[ee] : 0;
            vv[j] = ok ? sval[ee] : 0.f;
        }
        s16x4 g[UNROLL_];
        #pragma unroll
        for (int j = 0; j < UNROLL_; ++j)
            g[j] = *(const s16x4*)(ht + (size_t)cc[j] * C_);
        #pragma unroll
        for (int j = 0; j < UNROLL_; ++j) {
            #pragma unroll
            for (int q = 0; q < 4; ++q)
                acc[q] += vv[j] * bf16f(g[j][q]);
        }
    }
    size_t oi = (size_t)t * (N_ * C_) + (size_t)n * C_ + c;
    f32x4 xv = *(const f32x4*)(x + oi);
    s16x4 o;
    #pragma unroll
    for (int j = 0; j < 4; ++j) o[j] = bf16bits(2.f * acc[j] - xv[j]);
    *(s16x4*)(tx2 + oi) = o;
}

// ---------------- GEMM: out[t] = [x|tx1|tx2][t] @ [W0;W1;W2][t] + bias[t]  (f32 out) -------------

__global__ __launch_bounds__(256) void gemm_kernel(const float* __restrict__ x,
                                                   const bf16* __restrict__ tx1,
                                                   const bf16* __restrict__ tx2,
                                                   const float* __restrict__ weight,
                                                   const float* __restrict__ bias,
                                                   float* __restrict__ out) {
    int t  = blockIdx.y;
    int m0 = blockIdx.x * 128;
    __shared__ short As[128][40];   // [row][k], +8 pad
    __shared__ short Bs[128][40];   // B^T: [n][k], +8 pad
    int tid  = threadIdx.x;
    int wave = tid >> 6, lane = tid & 63;
    int l15 = lane & 15, l4 = lane >> 4;

    f32x4 acc[2][8];
    for (int i = 0; i < 2; ++i)
        for (int j = 0; j < 8; ++j) acc[i][j] = (f32x4){0.f, 0.f, 0.f, 0.f};

    size_t tslice = (size_t)t * N_ * C_;

    for (int ks = 0; ks < 12; ++ks) {
        int sid = ks >> 2;
        int i0  = (ks & 3) * 32;
        for (int slot = tid; slot < 512; slot += 256) {
            int r = slot >> 2, seg = slot & 3;
            int gr = m0 + r;
            int4 v = {0, 0, 0, 0};
            if (gr < N_) {
                if (sid == 0) {
                    const float* p = x + tslice + (size_t)gr * C_ + i0 + seg * 8;
                    union { int4 v; short s[8]; } u;
                    #pragma unroll
                    for (int j = 0; j < 8; ++j) u.s[j] = bf16bits(p[j]);
                    v = u.v;
                } else {
                    const bf16* p = (sid == 1 ? tx1 : tx2) + tslice + (size_t)gr * C_ + i0 + seg * 8;
                    v = *(const int4*)p;
                }
            }
            *(int4*)&As[r][seg * 8] = v;
        }
        const float* W = weight + (((size_t)t * K_ + sid) * C_ + i0) * C_;
        for (int slot = tid; slot < 512; slot += 256) {
            int r = slot >> 4, seg = slot & 15;
            const float* p = W + (size_t)r * C_ + seg * 8;
            #pragma unroll
            for (int j = 0; j < 8; ++j) Bs[seg * 8 + j][r] = bf16bits(p[j]);
        }
        __syncthreads();

        int krow = l4 * 8;
        bf16x8 bfr[8];
        #pragma unroll
        for (int nf = 0; nf < 8; ++nf)
            bfr[nf] = *(bf16x8*)&Bs[nf * 16 + l15][krow];
        #pragma unroll
        for (int mf = 0; mf < 2; ++mf) {
            bf16x8 a = *(bf16x8*)&As[wave * 32 + mf * 16 + l15][krow];
            #pragma unroll
            for (int nf = 0; nf < 8; ++nf)
                acc[mf][nf] = __builtin_amdgcn_mfma_f32_16x16x32_bf16(a, bfr[nf], acc[mf][nf], 0, 0, 0);
        }
        __syncthreads();
    }

    const float* bs = bias + (size_t)t * C_;
    float* ot = out + tslice;
    #pragma unroll
    for (int nf = 0; nf < 8; ++nf) {
        int gc = nf * 16 + l15;
        float bv = bs[gc];
        #pragma unroll
        for (int mf = 0; mf < 2; ++mf) {
            #pragma unroll
            for (int reg = 0; reg < 4; ++reg) {
                int gr = m0 + wave * 32 + mf * 16 + l4 * 4 + reg;
                if (gr < N_) ot[(size_t)gr * C_ + gc] = acc[mf][nf][reg] + bv;
            }
        }
    }
}

// ---------------- launch ----------------

extern "C" void kernel_launch(void* const* d_in, const int* in_sizes, int n_in,
                              void* d_out, int out_size, void* d_ws, size_t ws_size,
                              hipStream_t stream) {
    const float* x      = (const float*)d_in[0];
    const int*   erow   = (const int*)d_in[1];
    const int*   ecol   = (const int*)d_in[2];
    const float* eval   = (const float*)d_in[3];
    const float* weight = (const float*)d_in[4];
    const float* bias   = (const float*)d_in[5];
    float* out = (float*)d_out;

    char* ws = (char*)d_ws;
    size_t off = 0;
    auto alloc = [&](size_t bytes) -> void* {
        void* p = ws + off;
        off += (bytes + 255) & ~(size_t)255;
        return p;
    };
    int*   counts  = (int*)alloc((N_ + 1) * sizeof(int));
    int*   starts  = (int*)alloc((N_ + 1) * sizeof(int));
    int*   cursors = (int*)alloc((size_t)N_ * sizeof(int));
    int*   scol    = (int*)alloc((size_t)E_ * sizeof(int));
    float* sval    = (float*)alloc((size_t)E_ * sizeof(float));
    bf16*  tx1     = (bf16*)alloc((size_t)T_ * N_ * C_ * sizeof(bf16));
    bf16*  tx2     = (bf16*)alloc((size_t)T_ * N_ * C_ * sizeof(bf16));

    hipMemsetAsync(counts, 0, (N_ + 1) * sizeof(int), stream);
    count_kernel<<<(E_ + 255) / 256, 256, 0, stream>>>(erow, counts);
    scan_kernel<<<1, 1024, 0, stream>>>(counts, starts, cursors);
    scatter_kernel<<<(E_ + 255) / 256, 256, 0, stream>>>(erow, ecol, eval, cursors, scol, sval);
    spmm1_kernel<<<N_, 128, 0, stream>>>(starts, scol, sval, x, tx1);
    spmm2_kernel<<<N_, 128, 0, stream>>>(starts, scol, sval, tx1, x, tx2);
    dim3 g((N_ + 127) / 128, T_);
    gemm_kernel<<<g, 256, 0, stream>>>(x, tx1, tx2, weight, bias, out);
}